// Round 17
// baseline (227.951 us; speedup 1.0000x reference)
//
#include <hip/hip_runtime.h>

#define B_ 2
#define S_ 2048
#define DM_ 1024
#define H_ 16
#define HD_ 64
// Q pre-scale = HD^-0.5 * log2(e) so attention uses exp2 (bare v_exp_f32).
#define QSCALE_ 0.18033688011112042f

// Settled R0-R4: inputs fp32 (bf16-rounded values), output fp32.
typedef __bf16 bf16;
typedef __attribute__((ext_vector_type(4))) __bf16 bf16x4;
typedef __attribute__((ext_vector_type(8))) __bf16 bf16x8;
typedef __attribute__((ext_vector_type(4))) float f32x4;

#define MFMA16(a, b, c) __builtin_amdgcn_mfma_f32_16x16x32_bf16((a), (b), (c), 0, 0, 0)
#define EXP2(x) __builtin_amdgcn_exp2f(x)

__device__ __forceinline__ void async16(const bf16* g, bf16* l) {
  __builtin_amdgcn_global_load_lds(
      (const __attribute__((address_space(1))) void*)g,
      (__attribute__((address_space(3))) void*)l, 16, 0, 0);
}

// ---------------------------------------------------------------------------
// Convert pass, WEIGHTS ONLY (4x1M elems). Activations are now converted
// in-flight by qkv's A-staging (saves ~96MB of convert+re-read traffic).
// ---------------------------------------------------------------------------
__global__ __launch_bounds__(256) void convert_kernel(
    const float* __restrict__ wq, const float* __restrict__ wk,
    const float* __restrict__ wv, const float* __restrict__ wo,
    bf16* __restrict__ dst) {
  size_t idx = ((size_t)blockIdx.x * 256 + threadIdx.x) * 8;
  const float* src;
  size_t off;
  if (idx < 1048576) { src = wq; off = idx; }
  else if (idx < 2097152) { src = wk; off = idx - 1048576; }
  else if (idx < 3145728) { src = wv; off = idx - 2097152; }
  else { src = wo; off = idx - 3145728; }
  float4 a = *(const float4*)(src + off);
  float4 b = *(const float4*)(src + off + 4);
  bf16x8 o;
  o[0] = (bf16)a.x; o[1] = (bf16)a.y; o[2] = (bf16)a.z; o[3] = (bf16)a.w;
  o[4] = (bf16)b.x; o[5] = (bf16)b.y; o[6] = (bf16)b.z; o[7] = (bf16)b.w;
  *(bf16x8*)(dst + idx) = o;
}

// ---------------------------------------------------------------------------
// GEMM 128x128, BK=64, XOR-swizzled LDS. AF32=1: A staged from fp32 via
// float4x2 -> cvt -> ds_write_b128 (same swizzled granule layout); W always
// bf16 via global_load_lds. smem passed in (single buffer per kernel). m0/n0
// passed in (XCD-affinity decode by caller). MODE-2 Ct aliases smem.
// ---------------------------------------------------------------------------
template <int MODE, int AF32>
__device__ __forceinline__ void gemm_body(bf16* smem, const void* Av,
                                          const bf16* W, const float* bias,
                                          bf16* C, float scale, int m0,
                                          int n0) {
  constexpr int K = 1024;
  bf16* As = smem;
  bf16* Bs = smem + 128 * 64;
  const int t = threadIdx.x;
  const int lane = t & 63, wave = t >> 6;
  const int quad = lane >> 4, l16 = lane & 15;
  const int wm = (wave >> 1) * 64, wn = (wave & 1) * 64;

  const f32x4 zero = {0.f, 0.f, 0.f, 0.f};
  f32x4 acc[4][4];
  for (int i = 0; i < 4; i++)
    for (int j = 0; j < 4; j++) acc[i][j] = zero;

  for (int k0 = 0; k0 < K; k0 += 64) {
    for (int i = 0; i < 4; ++i) {
      int c = i * 256 + t;
      int row = c >> 3, g = c & 7;
      int off = k0 + ((g ^ (row & 7)) * 8);
      if (AF32) {
        const float* p = (const float*)Av + (size_t)(m0 + row) * K + off;
        float4 u0 = *(const float4*)p;
        float4 u1 = *(const float4*)(p + 4);
        bf16x8 v;
        v[0] = (bf16)u0.x; v[1] = (bf16)u0.y;
        v[2] = (bf16)u0.z; v[3] = (bf16)u0.w;
        v[4] = (bf16)u1.x; v[5] = (bf16)u1.y;
        v[6] = (bf16)u1.z; v[7] = (bf16)u1.w;
        *(bf16x8*)(As + c * 8) = v;
      } else {
        async16((const bf16*)Av + (size_t)(m0 + row) * K + off, As + c * 8);
      }
      async16(W + (size_t)(n0 + row) * K + off, Bs + c * 8);
    }
    __syncthreads();

    for (int ks = 0; ks < 2; ks++) {
      bf16x8 af[4], bfr[4];
      for (int mb = 0; mb < 4; mb++) {
        int ra = wm + mb * 16 + l16;
        af[mb] = *(const bf16x8*)(As + ra * 64 + ((ks * 4 + quad) ^ (ra & 7)) * 8);
        int rb = wn + mb * 16 + l16;
        bfr[mb] = *(const bf16x8*)(Bs + rb * 64 + ((ks * 4 + quad) ^ (rb & 7)) * 8);
      }
      for (int mb = 0; mb < 4; mb++)
        for (int nb = 0; nb < 4; nb++)
          acc[mb][nb] = MFMA16(af[mb], bfr[nb], acc[mb][nb]);
    }
    __syncthreads();  // also makes smem safe to reuse as Ct
  }

  if constexpr (MODE == 2) {
    bf16* Ct = smem;  // [128 cols][136]
    for (int nb = 0; nb < 4; nb++) {
      int cl = wn + nb * 16 + l16;
      float bv = bias[n0 + cl] * scale;
      for (int mb = 0; mb < 4; mb++) {
        int rowb = wm + mb * 16 + quad * 4;
        bf16x4 v;
        for (int r = 0; r < 4; r++)
          v[r] = (bf16)(acc[mb][nb][r] * scale + bv);
        *(bf16x4*)(Ct + cl * 136 + rowb) = v;
      }
    }
    __syncthreads();
    int c = t >> 1, half = t & 1;
    int colg = n0 + c;
    int hh = colg >> 6, dd = colg & 63;
    int bb = m0 >> 11, s0 = m0 & (S_ - 1);
    bf16* dst = C + (((size_t)(bb * H_ + hh)) * HD_ + dd) * S_ + s0 + half * 64;
    const bf16* srcr = Ct + c * 136 + half * 64;
    for (int j = 0; j < 8; ++j)
      *(bf16x8*)(dst + j * 8) = *(const bf16x8*)(srcr + j * 8);
  } else {
    for (int nb = 0; nb < 4; nb++) {
      int col = n0 + wn + nb * 16 + l16;
      float bv = bias[col] * scale;
      for (int mb = 0; mb < 4; mb++) {
        int rowb = m0 + wm + mb * 16 + quad * 4;
        for (int r = 0; r < 4; r++) {
          int row = rowb + r;
          float o = acc[mb][nb][r] * scale + bv;
          int bb = row >> 11, s = row & (S_ - 1);
          int h = col >> 6, d = col & 63;
          C[(((size_t)(bb * H_ + h)) * S_ + s) * HD_ + d] = (bf16)o;
        }
      }
    }
  }
}

// ---------------------------------------------------------------------------
// qkv: 1D grid 768, XCD-affinity decode (R16 win). A read directly from
// fp32 inputs (in-flight cvt); W from pre-converted bf16.
// ---------------------------------------------------------------------------
__global__ __launch_bounds__(256, 4) void qkv_proj_kernel(
    const float* Xq, const float* Xk, const float* Xv, const bf16* Wc,
    const float* bq, const float* bk, const float* bv, bf16* Qo, bf16* Ko,
    bf16* Vo) {
  __shared__ __align__(16) bf16 smem[128 * 136];  // 34816 B, one per block
  int bid = blockIdx.x;
  int z = bid >> 8;          // 256 blocks per z
  int r = bid & 255;
  int c = r & 7;             // XCD class (dispatch round-robin heuristic)
  int j = r >> 3;            // [0,32)
  int m0 = (c * 4 + (j & 3)) * 128;
  int n0 = (j >> 2) * 128;
  const bf16* W = Wc + (size_t)z * 1048576;
  if (z == 0)
    gemm_body<1, 1>(smem, Xq, W, bq, Qo, QSCALE_, m0, n0);  // Q pre-scaled
  else if (z == 1)
    gemm_body<1, 1>(smem, Xk, W, bk, Ko, 1.0f, m0, n0);
  else
    gemm_body<2, 1>(smem, Xv, W, bv, Vo, 1.0f, m0, n0);
}

// ---------------------------------------------------------------------------
// out_proj: 64x64 tiles, 1D grid 1024, XCD-affinity decode. BK=64, swizzled.
// ---------------------------------------------------------------------------
__global__ __launch_bounds__(256, 4) void out_proj_kernel(const bf16* A,
                                                          const bf16* W,
                                                          const float* bias,
                                                          float* C) {
  constexpr int K = 1024, N = 1024;
  __shared__ __align__(16) bf16 As[64 * 64];
  __shared__ __align__(16) bf16 Bs[64 * 64];
  const int t = threadIdx.x;
  const int lane = t & 63, wave = t >> 6;
  const int quad = lane >> 4, l16 = lane & 15;
  int bid = blockIdx.x;
  int c = bid & 7;
  int j = bid >> 3;  // [0,128)
  const int m0 = (c * 8 + (j & 7)) * 64;
  const int n0 = (j >> 3) * 64;

  const f32x4 zero = {0.f, 0.f, 0.f, 0.f};
  f32x4 acc[4];
  for (int i = 0; i < 4; i++) acc[i] = zero;

  for (int k0 = 0; k0 < K; k0 += 64) {
    for (int i = 0; i < 2; ++i) {
      int cc = i * 256 + t;
      int row = cc >> 3, g = cc & 7;
      int off = k0 + ((g ^ (row & 7)) * 8);
      async16(A + (size_t)(m0 + row) * K + off, As + cc * 8);
      async16(W + (size_t)(n0 + row) * K + off, Bs + cc * 8);
    }
    __syncthreads();

    for (int ks = 0; ks < 2; ks++) {
      int ra = wave * 16 + l16;
      bf16x8 af = *(const bf16x8*)(As + ra * 64 + ((ks * 4 + quad) ^ (ra & 7)) * 8);
      for (int nb = 0; nb < 4; nb++) {
        int rb = nb * 16 + l16;
        bf16x8 bfr =
            *(const bf16x8*)(Bs + rb * 64 + ((ks * 4 + quad) ^ (rb & 7)) * 8);
        acc[nb] = MFMA16(af, bfr, acc[nb]);
      }
    }
    __syncthreads();
  }

  for (int nb = 0; nb < 4; nb++) {
    int col = n0 + nb * 16 + l16;
    float bv = bias[col];
    int rowb = m0 + wave * 16 + quad * 4;
    for (int r = 0; r < 4; r++)
      C[(size_t)(rowb + r) * N + col] = acc[nb][r] + bv;
  }
}

// ---------------------------------------------------------------------------
// Flash attention, softmax-one, S^T order (R14 shape, frozen: 53-55us).
// Block = 4 waves = 2 q-halves x 2 key-halves of a (128q x 128key) tile;
// 4 qsets/wave; kf/vf reads feed 4 MFMA each. Grid 512 = 2/CU. XCD decode
// id&31 -> (b,h). exp2 (Q pre-scaled by log2e); no max-tracking;
// denom = 1 + sum.
// ---------------------------------------------------------------------------
__global__ __launch_bounds__(256, 2) void attn_kernel(
    const bf16* __restrict__ Q, const bf16* __restrict__ Kg,
    const bf16* __restrict__ VTg, bf16* __restrict__ O) {
  __shared__ __align__(16) bf16 Ks[128 * 64];     // XOR-swizzled granules
  __shared__ __align__(16) bf16 Vt[64 * 128];     // XOR-swizzled granules
  __shared__ __align__(16) bf16 Ps[4 * 64 * 72];  // per-wave P^T (36.9KB)
  __shared__ float rsL[2][64];                    // key-half rs exchange
  const int t = threadIdx.x;
  const int lane = t & 63, wave = t >> 6;
  const int quad = lane >> 4, l16 = lane & 15;
  const int id = blockIdx.x;
  const int bh = id & 31;  // (b,h): fixes XCD class (id%8 = bh%8)
  const int qt = id >> 5;
  const int q0 = qt * 128;
  const int b = bh >> 4, h = bh & 15;
  const int qhalf = wave >> 1, khalf = wave & 1;
  const size_t base = ((size_t)(b * H_ + h)) * S_ * HD_;
  const bf16* Qp = Q + base;
  const bf16* Kp = Kg + base;
  const bf16* Vp = VTg + base;  // [HD][S]

  // Q fragments: 4 qsets of 16 rows; rows q0 + qhalf*64 + s*16 + l16
  bf16x8 aq[4][2];
  for (int s = 0; s < 4; s++) {
    const bf16* qr = Qp + (size_t)(q0 + qhalf * 64 + s * 16 + l16) * HD_;
    aq[s][0] = *(const bf16x8*)(qr + quad * 8);
    aq[s][1] = *(const bf16x8*)(qr + 32 + quad * 8);
  }

  const f32x4 zero = {0.f, 0.f, 0.f, 0.f};
  f32x4 oc[4][4];  // [qset][dim-block]
  for (int s = 0; s < 4; s++)
    for (int d = 0; d < 4; d++) oc[s][d] = zero;
  float rs[4] = {0.f, 0.f, 0.f, 0.f};

  bf16* Pw = Ps + wave * (64 * 72);

  for (int kv0 = 0; kv0 < S_; kv0 += 128) {
    for (int i = 0; i < 4; ++i) {
      int c = i * 256 + t;
      int row = c >> 3, g = c & 7;
      async16(Kp + (size_t)(kv0 + row) * HD_ + (g ^ (row & 7)) * 8, Ks + c * 8);
    }
    for (int i = 0; i < 4; ++i) {
      int c = i * 256 + t;
      int d = c >> 4, g = c & 15;
      async16(Vp + (size_t)d * S_ + kv0 + (g ^ (d & 15)) * 8, Vt + c * 8);
    }
    __syncthreads();

    // S^T = K Q^T over this wave's 64 keys (khalf) x 64 q (qhalf)
    f32x4 sc[4][4];
    for (int s = 0; s < 4; s++)
      for (int nb = 0; nb < 4; nb++) sc[s][nb] = zero;
    for (int ks = 0; ks < 2; ks++) {
      for (int nb = 0; nb < 4; nb++) {
        int row = khalf * 64 + nb * 16 + l16;
        int slot = (ks * 4 + quad) ^ (row & 7);
        bf16x8 kf = *(const bf16x8*)(Ks + row * 64 + slot * 8);
        for (int s = 0; s < 4; s++)
          sc[s][nb] = MFMA16(kf, aq[s][ks], sc[s][nb]);
      }
    }

    // exp2 + packed P^T write (rows = q local 0..63, cols = 64 local keys)
    for (int s = 0; s < 4; s++) {
      bf16* prow = Pw + (s * 16 + l16) * 72 + quad * 4;
      for (int nb = 0; nb < 4; nb++) {
        float p0 = EXP2(sc[s][nb][0]);
        float p1 = EXP2(sc[s][nb][1]);
        float p2 = EXP2(sc[s][nb][2]);
        float p3 = EXP2(sc[s][nb][3]);
        rs[s] += (p0 + p1) + (p2 + p3);
        bf16x4 pv = {(bf16)p0, (bf16)p1, (bf16)p2, (bf16)p3};
        *(bf16x4*)(prow + nb * 16) = pv;
      }
    }
    // Pw wave-private; in-order DS pipe orders write->read (no barrier).

    // O += P V over local keys (2 segs of 32); vf shared across 4 qsets
    for (int ks2 = 0; ks2 < 2; ks2++) {
      bf16x8 vf[4];
      for (int db = 0; db < 4; db++) {
        int row = db * 16 + l16;
        int g = khalf * 8 + ks2 * 4 + quad;
        vf[db] = *(const bf16x8*)(Vt + row * 128 + (g ^ (row & 15)) * 8);
      }
      for (int s = 0; s < 4; s++) {
        bf16x8 ap =
            *(const bf16x8*)(Pw + (s * 16 + l16) * 72 + ks2 * 32 + quad * 8);
        for (int db = 0; db < 4; db++)
          oc[s][db] = MFMA16(ap, vf[db], oc[s][db]);
      }
    }
    __syncthreads();  // protect Ks/Vt/Ps before next tile
  }

  // epilogue: combine key-halves through LDS (Ps reused as fp32 scratch)
  float* Ld = (float*)Ps;  // [2 pairs][64 q][68]
  if (khalf) {
    for (int s = 0; s < 4; s++) {
      float rtot = rs[s];
      rtot += __shfl_xor(rtot, 16);
      rtot += __shfl_xor(rtot, 32);
      if (quad == 0) rsL[qhalf][s * 16 + l16] = rtot;
      for (int db = 0; db < 4; db++)
        for (int r = 0; r < 4; r++)
          Ld[(size_t)qhalf * (64 * 68) + (s * 16 + quad * 4 + r) * 68 +
             db * 16 + l16] = oc[s][db][r];
    }
  }
  __syncthreads();
  if (!khalf) {
    for (int s = 0; s < 4; s++) {
      float rtot = rs[s];
      rtot += __shfl_xor(rtot, 16);
      rtot += __shfl_xor(rtot, 32);
      float l_all = 1.f + rtot + rsL[qhalf][s * 16 + l16];
      for (int r = 0; r < 4; r++) {
        float inv = 1.f / __shfl(l_all, quad * 4 + r);
        int qrow = q0 + qhalf * 64 + s * 16 + quad * 4 + r;
        size_t orow = ((size_t)(b * S_ + qrow) * H_ + h) * HD_;
        for (int db = 0; db < 4; db++) {
          float val = oc[s][db][r] +
                      Ld[(size_t)qhalf * (64 * 68) +
                         (s * 16 + quad * 4 + r) * 68 + db * 16 + l16];
          O[orow + db * 16 + l16] = (bf16)(val * inv);
        }
      }
    }
  }
}

// ---------------------------------------------------------------------------
extern "C" void kernel_launch(void* const* d_in, const int* in_sizes, int n_in,
                              void* d_out, int out_size, void* d_ws,
                              size_t ws_size, hipStream_t stream) {
  const float* query = (const float*)d_in[0];
  const float* key = (const float*)d_in[1];
  const float* value = (const float*)d_in[2];
  const float* bq = (const float*)d_in[4];
  const float* bk = (const float*)d_in[6];
  const float* bv = (const float*)d_in[8];
  const float* bo = (const float*)d_in[10];
  float* out = (float*)d_out;

  // ws layout (bf16 elems): Wc[4M] | Qw[4M] | Kw[4M] | Vw[4M] | Ow[4M]
  bf16* Wc = (bf16*)d_ws;  // converted weights: Wq|Wk|Wv|Wo
  bf16* Qw = Wc + 4194304;
  const size_t SZ = (size_t)B_ * H_ * S_ * HD_;  // 4M
  bf16* Kw = Qw + SZ;
  bf16* Vw = Kw + SZ;  // V^T, [B,H,HD,S]
  bf16* Ow = Vw + SZ;  // [B,S,H,HD]

  convert_kernel<<<2048, 256, 0, stream>>>((const float*)d_in[3],
                                           (const float*)d_in[5],
                                           (const float*)d_in[7],
                                           (const float*)d_in[9], Wc);
  qkv_proj_kernel<<<768, 256, 0, stream>>>(query, key, value, Wc, bq, bk, bv,
                                           Qw, Kw, Vw);
  attn_kernel<<<512, 256, 0, stream>>>(Qw, Kw, Vw, Ow);
  out_proj_kernel<<<1024, 256, 0, stream>>>(Ow, Wc + 3145728, bo, out);
}